// Round 6
// baseline (313.850 us; speedup 1.0000x reference)
//
#include <hip/hip_runtime.h>

#define BN_EPS 1e-5f
#define NBUF 64   // spread buffers for stat atomics

typedef float        f32x4 __attribute__((ext_vector_type(4)));
typedef float        f32x2 __attribute__((ext_vector_type(2)));
typedef unsigned int u32x2 __attribute__((ext_vector_type(2)));
typedef unsigned int u32x4 __attribute__((ext_vector_type(4)));

__device__ inline unsigned pack_bf16(float a, float b) {
    unsigned ua = __float_as_uint(a);
    unsigned ub = __float_as_uint(b);
    ua = (ua + 0x7fffu + ((ua >> 16) & 1u)) >> 16;
    ub = (ub + 0x7fffu + ((ub >> 16) & 1u)) >> 16;
    return ua | (ub << 16);
}
__device__ inline float bf_lo(unsigned u) { return __uint_as_float(u << 16); }
__device__ inline float bf_hi(unsigned u) { return __uint_as_float(u & 0xffff0000u); }

// ---------------------------------------------------------------------------
// Cast fp32 -> packed bf16 (RNE). One thread = 4 floats -> 2 uints.
// ---------------------------------------------------------------------------
__global__ void __launch_bounds__(256) cast_bf16_kernel(
    const f32x4* __restrict__ in, u32x2* __restrict__ out, int n4)
{
    const int t = blockIdx.x * 256 + threadIdx.x;
    if (t >= n4) return;
    const f32x4 v = in[t];
    u32x2 r;
    r.x = pack_bf16(v.x, v.y);
    r.y = pack_bf16(v.z, v.w);
    out[t] = r;
}

// ---------------------------------------------------------------------------
// Stage 0: Cin=4 (bf16 8B rows, 4MB L2-resident), Cout=16.
// idx via coalesced LDS staging (stride-27 read = conflict-free);
// all 27 gathers in flight (L1-bypass); W via wave-uniform scalar loads.
// ---------------------------------------------------------------------------
__global__ void __launch_bounds__(256) conv0_kernel(
    const unsigned long long* __restrict__ xb, const int* __restrict__ neigh,
    const float* __restrict__ W, float* __restrict__ y,
    float* __restrict__ stats)
{
    __shared__ int idxlds[256 * 27];
    {
        const size_t base = (size_t)blockIdx.x * (256 * 27);
        for (int i = threadIdx.x; i < 256 * 27; i += 256)
            idxlds[i] = neigh[base + i];
    }
    __syncthreads();

    const int node = blockIdx.x * 256 + threadIdx.x;

    unsigned long long xr[27];
#pragma unroll
    for (int j = 0; j < 27; ++j) {
        const int nb = idxlds[threadIdx.x * 27 + j];
        xr[j] = __hip_atomic_load(xb + nb, __ATOMIC_RELAXED,
                                  __HIP_MEMORY_SCOPE_AGENT);
    }

    float acc[16];
#pragma unroll
    for (int c = 0; c < 16; ++c) acc[c] = 0.f;

#pragma unroll
    for (int j = 0; j < 27; ++j) {
        const unsigned lo = (unsigned)xr[j];
        const unsigned hi = (unsigned)(xr[j] >> 32);
        float xv[4];
        xv[0] = bf_lo(lo); xv[1] = bf_hi(lo);
        xv[2] = bf_lo(hi); xv[3] = bf_hi(hi);
#pragma unroll
        for (int kk = 0; kk < 4; ++kk) {
            // wave-uniform address -> compiler emits scalar (s_load) reads
            const f32x4* wr = (const f32x4*)(W + (j * 4 + kk) * 16);
#pragma unroll
            for (int c4 = 0; c4 < 4; ++c4) {
                const f32x4 w = wr[c4];
                acc[c4 * 4 + 0] = fmaf(xv[kk], w.x, acc[c4 * 4 + 0]);
                acc[c4 * 4 + 1] = fmaf(xv[kk], w.y, acc[c4 * 4 + 1]);
                acc[c4 * 4 + 2] = fmaf(xv[kk], w.z, acc[c4 * 4 + 2]);
                acc[c4 * 4 + 3] = fmaf(xv[kk], w.w, acc[c4 * 4 + 3]);
            }
        }
    }

    f32x4* yr = (f32x4*)(y + (size_t)node * 16);
#pragma unroll
    for (int c4 = 0; c4 < 4; ++c4) {
        f32x4 v = { acc[c4 * 4 + 0], acc[c4 * 4 + 1], acc[c4 * 4 + 2], acc[c4 * 4 + 3] };
        __builtin_nontemporal_store(v, yr + c4);
    }

    float* buf = stats + (blockIdx.x & (NBUF - 1)) * (2 * 16);
#pragma unroll
    for (int c = 0; c < 16; ++c) {
        float v = acc[c];
        float q = v * v;
#pragma unroll
        for (int off = 32; off > 0; off >>= 1) {
            v += __shfl_xor(v, off, 64);
            q += __shfl_xor(q, off, 64);
        }
        if ((threadIdx.x & 63) == 0) {
            atomicAdd(&buf[c], v);
            atomicAdd(&buf[16 + c], q);
        }
    }
}

// ---------------------------------------------------------------------------
// Stage 1: Cin=16 (bf16 32B rows, 2MB L2-resident), Cout=32, SINGLE gather
// pass. j-split: threads 0-127 do j=0..13 of node ln, threads 128-255 do
// j=14..26; partials combined via padded-LDS reduction. W scalar-loaded.
// Grid: N5/128 = 512 blocks.
// ---------------------------------------------------------------------------
__global__ void __launch_bounds__(256) conv1_kernel(
    const u32x4* __restrict__ xb, const int* __restrict__ neigh,
    const float* __restrict__ W, float* __restrict__ y,
    float* __restrict__ stats)
{
    __shared__ int sh[128 * 33];            // idx phase: 128*27; reduce: 128*33
    int*   idxlds = sh;
    float* red    = (float*)sh;

    const int nbase = blockIdx.x * 128;
    for (int i = threadIdx.x; i < 128 * 27; i += 256)
        idxlds[i] = neigh[(size_t)nbase * 27 + i];
    __syncthreads();

    const int ln   = threadIdx.x & 127;
    const int half = threadIdx.x >> 7;       // 0: j 0..13, 1: j 14..26
    const int node = nbase + ln;
    const int js   = half ? 14 : 0;
    const int nj   = half ? 13 : 14;

    u32x4 xa[14], xc[14];
#pragma unroll
    for (int jj = 0; jj < 14; ++jj) {
        const int j = js + ((jj < nj) ? jj : 0);   // dup of first j on tail
        const size_t r = (size_t)idxlds[ln * 27 + j] * 2;
        xa[jj] = xb[r];
        xc[jj] = xb[r + 1];
    }

    float acc[32];
#pragma unroll
    for (int c = 0; c < 32; ++c) acc[c] = 0.f;

#pragma unroll
    for (int jj = 0; jj < 14; ++jj) {
        if (jj < nj) {                        // wave-uniform (half per wave)
            const int j = js + jj;
            float xv[16];
            xv[0]  = bf_lo(xa[jj].x); xv[1]  = bf_hi(xa[jj].x);
            xv[2]  = bf_lo(xa[jj].y); xv[3]  = bf_hi(xa[jj].y);
            xv[4]  = bf_lo(xa[jj].z); xv[5]  = bf_hi(xa[jj].z);
            xv[6]  = bf_lo(xa[jj].w); xv[7]  = bf_hi(xa[jj].w);
            xv[8]  = bf_lo(xc[jj].x); xv[9]  = bf_hi(xc[jj].x);
            xv[10] = bf_lo(xc[jj].y); xv[11] = bf_hi(xc[jj].y);
            xv[12] = bf_lo(xc[jj].z); xv[13] = bf_hi(xc[jj].z);
            xv[14] = bf_lo(xc[jj].w); xv[15] = bf_hi(xc[jj].w);
#pragma unroll
            for (int k = 0; k < 16; ++k) {
                const f32x4* wr = (const f32x4*)(W + ((size_t)(j * 16 + k)) * 32);
#pragma unroll
                for (int c4 = 0; c4 < 8; ++c4) {
                    const f32x4 w = wr[c4];
                    acc[c4 * 4 + 0] = fmaf(xv[k], w.x, acc[c4 * 4 + 0]);
                    acc[c4 * 4 + 1] = fmaf(xv[k], w.y, acc[c4 * 4 + 1]);
                    acc[c4 * 4 + 2] = fmaf(xv[k], w.z, acc[c4 * 4 + 2]);
                    acc[c4 * 4 + 3] = fmaf(xv[k], w.w, acc[c4 * 4 + 3]);
                }
            }
        }
    }

    __syncthreads();                          // idxlds dead; red takes over
    if (half) {
#pragma unroll
        for (int c = 0; c < 32; ++c) red[ln * 33 + c] = acc[c];
    }
    __syncthreads();
    if (!half) {
#pragma unroll
        for (int c = 0; c < 32; ++c) acc[c] += red[ln * 33 + c];

        f32x4* yr = (f32x4*)(y + (size_t)node * 32);
#pragma unroll
        for (int c4 = 0; c4 < 8; ++c4) {
            f32x4 v = { acc[c4 * 4 + 0], acc[c4 * 4 + 1], acc[c4 * 4 + 2], acc[c4 * 4 + 3] };
            __builtin_nontemporal_store(v, yr + c4);
        }

        float* buf = stats + (blockIdx.x & (NBUF - 1)) * (2 * 32);
#pragma unroll
        for (int c = 0; c < 32; ++c) {
            float v = acc[c];
            float q = v * v;
#pragma unroll
            for (int off = 32; off > 0; off >>= 1) {
                v += __shfl_xor(v, off, 64);
                q += __shfl_xor(q, off, 64);
            }
            if ((threadIdx.x & 63) == 0) {
                atomicAdd(&buf[c], v);
                atomicAdd(&buf[32 + c], q);
            }
        }
    }
}

// ---------------------------------------------------------------------------
// Stage 2: Cin=32 (bf16 64B rows), Cout=64. thread-per-(node, channel-quad),
// 16 nodes/block, idx in LDS, W fp32 straight from L2 (coalesced+reused).
// ---------------------------------------------------------------------------
__global__ void __launch_bounds__(256) conv2_kernel(
    const u32x4* __restrict__ xb, const int* __restrict__ neigh,
    const float* __restrict__ W, float* __restrict__ y,
    float* __restrict__ stats)
{
    __shared__ int idxlds[16 * 27];
    const int nbase = blockIdx.x * 16;
    for (int i = threadIdx.x; i < 16 * 27; i += 256) {
        int n = i / 27, j = i - n * 27;
        idxlds[i] = neigh[(size_t)(nbase + n) * 27 + j];
    }
    __syncthreads();

    const int ln = threadIdx.x >> 4;
    const int c4 = threadIdx.x & 15;
    const int node = nbase + ln;

    f32x4 acc = { 0.f, 0.f, 0.f, 0.f };

#pragma unroll 1
    for (int j = 0; j < 27; ++j) {
        const int nb = idxlds[ln * 27 + j];
        const u32x4* xr = xb + (size_t)nb * 4;
        u32x4 xq[4];
#pragma unroll
        for (int q = 0; q < 4; ++q) xq[q] = xr[q];
#pragma unroll
        for (int q = 0; q < 4; ++q) {
            float xv[8];
            xv[0] = bf_lo(xq[q].x); xv[1] = bf_hi(xq[q].x);
            xv[2] = bf_lo(xq[q].y); xv[3] = bf_hi(xq[q].y);
            xv[4] = bf_lo(xq[q].z); xv[5] = bf_hi(xq[q].z);
            xv[6] = bf_lo(xq[q].w); xv[7] = bf_hi(xq[q].w);
#pragma unroll
            for (int h = 0; h < 8; ++h) {
                const int k = q * 8 + h;
                const f32x4 w = *(const f32x4*)(W + ((size_t)j * 32 + k) * 64 + c4 * 4);
                acc.x = fmaf(xv[h], w.x, acc.x);
                acc.y = fmaf(xv[h], w.y, acc.y);
                acc.z = fmaf(xv[h], w.z, acc.z);
                acc.w = fmaf(xv[h], w.w, acc.w);
            }
        }
    }

    __builtin_nontemporal_store(acc, (f32x4*)(y + (size_t)node * 64 + c4 * 4));

    float sx = acc.x, sy = acc.y, sz = acc.z, sw = acc.w;
    float qx = acc.x * acc.x, qy = acc.y * acc.y, qz = acc.z * acc.z, qw = acc.w * acc.w;
#pragma unroll
    for (int off = 16; off <= 32; off <<= 1) {
        sx += __shfl_xor(sx, off, 64);  sy += __shfl_xor(sy, off, 64);
        sz += __shfl_xor(sz, off, 64);  sw += __shfl_xor(sw, off, 64);
        qx += __shfl_xor(qx, off, 64);  qy += __shfl_xor(qy, off, 64);
        qz += __shfl_xor(qz, off, 64);  qw += __shfl_xor(qw, off, 64);
    }
    if ((threadIdx.x & 63) < 16) {
        float* buf = stats + (blockIdx.x & (NBUF - 1)) * (2 * 64);
        atomicAdd(&buf[c4 * 4 + 0], sx);
        atomicAdd(&buf[c4 * 4 + 1], sy);
        atomicAdd(&buf[c4 * 4 + 2], sz);
        atomicAdd(&buf[c4 * 4 + 3], sw);
        atomicAdd(&buf[64 + c4 * 4 + 0], qx);
        atomicAdd(&buf[64 + c4 * 4 + 1], qy);
        atomicAdd(&buf[64 + c4 * 4 + 2], qz);
        atomicAdd(&buf[64 + c4 * 4 + 3], qw);
    }
}

// ---------------------------------------------------------------------------
// Fused BN-finalize (per-block recompute) + affine + ReLU + 8-sibling maxpool.
// ---------------------------------------------------------------------------
template<int COUT, bool BF16OUT>
__global__ void __launch_bounds__(256) pool_fin_kernel(
    const float* __restrict__ y, const float* __restrict__ stats,
    const float* __restrict__ gamma, const float* __restrict__ beta,
    void* __restrict__ xout, float invN, int total2)
{
    __shared__ float ss[2 * COUT];
    if (threadIdx.x < COUT) {
        const int c = threadIdx.x;
        float s = 0.f, q = 0.f;
        for (int b = 0; b < NBUF; ++b) {
            s += stats[b * 2 * COUT + c];
            q += stats[b * 2 * COUT + COUT + c];
        }
        const float mean = s * invN;
        const float var  = fmaf(-mean, mean, q * invN);
        const float sc   = gamma[c] * rsqrtf(var + BN_EPS);
        ss[c]        = sc;
        ss[COUT + c] = fmaf(-mean, sc, beta[c]);
    }
    __syncthreads();

    const int t = blockIdx.x * 256 + threadIdx.x;
    if (t >= total2) return;
    const int p  = t / (COUT / 2);
    const int c2 = (t % (COUT / 2)) * 2;
    const float sc0 = ss[c2],     sh0 = ss[COUT + c2];
    const float sc1 = ss[c2 + 1], sh1 = ss[COUT + c2 + 1];
    const float* yr = y + (size_t)p * 8 * COUT + c2;
    float m0 = -3.4e38f, m1 = -3.4e38f;
#pragma unroll
    for (int i = 0; i < 8; ++i) {
        const f32x2 v = __builtin_nontemporal_load((const f32x2*)(yr + i * COUT));
        m0 = fmaxf(m0, fmaf(v.x, sc0, sh0));
        m1 = fmaxf(m1, fmaf(v.y, sc1, sh1));
    }
    m0 = fmaxf(m0, 0.f);
    m1 = fmaxf(m1, 0.f);
    if (BF16OUT) {
        ((unsigned*)xout)[t] = pack_bf16(m0, m1);
    } else {
        f32x2 r = { m0, m1 };
        ((f32x2*)xout)[t] = r;
    }
}

// ---------------------------------------------------------------------------
// octree2voxel scatter with transpose: out[b][c][i][j][k] = x3[n][c], r=vox[n]
// ---------------------------------------------------------------------------
__global__ void __launch_bounds__(256) scatter_kernel(
    const float* __restrict__ x3, const int* __restrict__ vox,
    float* __restrict__ out)
{
    const int t = blockIdx.x * 256 + threadIdx.x;  // 1024*64 threads
    const int n = t >> 6, c = t & 63;
    const int r = vox[n];
    out[((r >> 9) << 15) + (c << 9) + (r & 511)] = x3[t];
}

extern "C" void kernel_launch(void* const* d_in, const int* in_sizes, int n_in,
                              void* d_out, int out_size, void* d_ws, size_t ws_size,
                              hipStream_t stream)
{
    const float* data = (const float*)d_in[0];
    const float* W0   = (const float*)d_in[1];
    const float* g0   = (const float*)d_in[2];
    const float* b0   = (const float*)d_in[3];
    const float* W1   = (const float*)d_in[4];
    const float* g1   = (const float*)d_in[5];
    const float* b1   = (const float*)d_in[6];
    const float* W2   = (const float*)d_in[7];
    const float* g2   = (const float*)d_in[8];
    const float* b2   = (const float*)d_in[9];
    const int* neigh0 = (const int*)d_in[10];
    const int* neigh1 = (const int*)d_in[11];
    const int* neigh2 = (const int*)d_in[12];
    const int* vox    = (const int*)d_in[13];

    const int N6 = 524288, N5 = 65536, N4 = 8192, N3 = 1024;

    float* ws = (float*)d_ws;
    const size_t off_y0  = 0;                                 // N6*16
    const size_t off_xb1 = off_y0 + (size_t)N6 * 16;          // N5*8  (bf16 x1)
    const size_t off_y1  = off_xb1 + (size_t)N5 * 8;          // N5*32
    const size_t off_xb0 = off_y1;                            // N6*2  (bf16 x0, alias)
    const size_t off_xb2 = off_y1 + (size_t)N5 * 32;          // N4*16 (bf16 x2)
    const size_t off_y2  = off_xb2 + (size_t)N4 * 16;         // N4*64
    const size_t off_x3  = off_y2 + (size_t)N4 * 64;          // N3*64
    const size_t off_st0 = off_x3 + (size_t)N3 * 64;          // NBUF*2*16
    const size_t off_st1 = off_st0 + NBUF * 2 * 16;           // NBUF*2*32
    const size_t off_st2 = off_st1 + NBUF * 2 * 32;           // NBUF*2*64

    (void)hipMemsetAsync(ws + off_st0, 0, (size_t)(NBUF * 2 * (16 + 32 + 64)) * sizeof(float), stream);

    // stage 0: cast data -> bf16 table (4MB), conv with L1-bypass gathers
    cast_bf16_kernel<<<N6 / 256, 256, 0, stream>>>(
        (const f32x4*)data, (u32x2*)(ws + off_xb0), N6);
    conv0_kernel<<<N6 / 256, 256, 0, stream>>>(
        (const unsigned long long*)(ws + off_xb0), neigh0, W0, ws + off_y0, ws + off_st0);
    pool_fin_kernel<16, true><<<(N5 * 8) / 256, 256, 0, stream>>>(
        ws + off_y0, ws + off_st0, g0, b0, ws + off_xb1, 1.f / N6, N5 * 8);

    // stage 1: single gather pass, j-split across thread halves
    conv1_kernel<<<N5 / 128, 256, 0, stream>>>(
        (const u32x4*)(ws + off_xb1), neigh1, W1, ws + off_y1, ws + off_st1);
    pool_fin_kernel<32, true><<<(N4 * 16) / 256, 256, 0, stream>>>(
        ws + off_y1, ws + off_st1, g1, b1, ws + off_xb2, 1.f / N5, N4 * 16);

    // stage 2
    conv2_kernel<<<N4 / 16, 256, 0, stream>>>(
        (const u32x4*)(ws + off_xb2), neigh2, W2, ws + off_y2, ws + off_st2);
    pool_fin_kernel<64, false><<<(N3 * 32) / 256, 256, 0, stream>>>(
        ws + off_y2, ws + off_st2, g2, b2, ws + off_x3, 1.f / N4, N3 * 32);

    // octree2voxel
    (void)hipMemsetAsync(d_out, 0, (size_t)out_size * sizeof(float), stream);
    scatter_kernel<<<(N3 * 64) / 256, 256, 0, stream>>>(ws + off_x3, vox, (float*)d_out);
}

// Round 7
// 249.514 us; speedup vs baseline: 1.2578x; 1.2578x over previous
//
#include <hip/hip_runtime.h>

#define BN_EPS 1e-5f
#define NBUF 64   // spread buffers for stat atomics

typedef float        f32x4 __attribute__((ext_vector_type(4)));
typedef float        f32x2 __attribute__((ext_vector_type(2)));
typedef unsigned int u32x2 __attribute__((ext_vector_type(2)));
typedef unsigned int u32x4 __attribute__((ext_vector_type(4)));

__device__ inline unsigned pack_bf16(float a, float b) {
    unsigned ua = __float_as_uint(a);
    unsigned ub = __float_as_uint(b);
    ua = (ua + 0x7fffu + ((ua >> 16) & 1u)) >> 16;
    ub = (ub + 0x7fffu + ((ub >> 16) & 1u)) >> 16;
    return ua | (ub << 16);
}
__device__ inline float bf_lo(unsigned u) { return __uint_as_float(u << 16); }
__device__ inline float bf_hi(unsigned u) { return __uint_as_float(u & 0xffff0000u); }

// ---------------------------------------------------------------------------
// Cast fp32 -> packed bf16 (RNE). One thread = 4 floats -> 2 uints.
// ---------------------------------------------------------------------------
__global__ void __launch_bounds__(256) cast_bf16_kernel(
    const f32x4* __restrict__ in, u32x2* __restrict__ out, int n4)
{
    const int t = blockIdx.x * 256 + threadIdx.x;
    if (t >= n4) return;
    const f32x4 v = in[t];
    u32x2 r;
    r.x = pack_bf16(v.x, v.y);
    r.y = pack_bf16(v.z, v.w);
    out[t] = r;
}

// ---------------------------------------------------------------------------
// Stage 0: Cin=4 (bf16 8B rows, 4MB L2-resident), Cout=16.
// idx: coalesced global->LDS staging, stride-27 read (odd stride, 2-way = free).
// Gathers: all 27 in flight, agent-scope relaxed (sc0 -> L1 bypass, L2 direct).
// W: LDS broadcast reads (wave-uniform ds_read_b128, conflict-free).
// LDS 34.5KB -> 4 blocks/CU -> 16 waves/CU.
// ---------------------------------------------------------------------------
__global__ void __launch_bounds__(256) conv0_kernel(
    const unsigned long long* __restrict__ xb, const int* __restrict__ neigh,
    const float* __restrict__ W, float* __restrict__ y,
    float* __restrict__ stats)
{
    __shared__ int   idxlds[256 * 27];
    __shared__ float Wlds[27 * 4 * 16];

    for (int i = threadIdx.x; i < 27 * 4 * 16; i += 256) Wlds[i] = W[i];
    {
        const size_t base = (size_t)blockIdx.x * (256 * 27);
        for (int i = threadIdx.x; i < 256 * 27; i += 256)
            idxlds[i] = neigh[base + i];
    }
    __syncthreads();

    const int node = blockIdx.x * 256 + threadIdx.x;

    unsigned long long xr[27];
#pragma unroll
    for (int j = 0; j < 27; ++j) {
        const int nb = idxlds[threadIdx.x * 27 + j];
        xr[j] = __hip_atomic_load(xb + nb, __ATOMIC_RELAXED,
                                  __HIP_MEMORY_SCOPE_AGENT);
    }

    float acc[16];
#pragma unroll
    for (int c = 0; c < 16; ++c) acc[c] = 0.f;

#pragma unroll
    for (int j = 0; j < 27; ++j) {
        const unsigned lo = (unsigned)xr[j];
        const unsigned hi = (unsigned)(xr[j] >> 32);
        float xv[4];
        xv[0] = bf_lo(lo); xv[1] = bf_hi(lo);
        xv[2] = bf_lo(hi); xv[3] = bf_hi(hi);
#pragma unroll
        for (int kk = 0; kk < 4; ++kk) {
            const f32x4* wv = (const f32x4*)&Wlds[(j * 4 + kk) * 16];
#pragma unroll
            for (int c4 = 0; c4 < 4; ++c4) {
                const f32x4 w = wv[c4];
                acc[c4 * 4 + 0] = fmaf(xv[kk], w.x, acc[c4 * 4 + 0]);
                acc[c4 * 4 + 1] = fmaf(xv[kk], w.y, acc[c4 * 4 + 1]);
                acc[c4 * 4 + 2] = fmaf(xv[kk], w.z, acc[c4 * 4 + 2]);
                acc[c4 * 4 + 3] = fmaf(xv[kk], w.w, acc[c4 * 4 + 3]);
            }
        }
    }

    f32x4* yr = (f32x4*)(y + (size_t)node * 16);
#pragma unroll
    for (int c4 = 0; c4 < 4; ++c4) {
        f32x4 v = { acc[c4 * 4 + 0], acc[c4 * 4 + 1], acc[c4 * 4 + 2], acc[c4 * 4 + 3] };
        __builtin_nontemporal_store(v, yr + c4);
    }

    float* buf = stats + (blockIdx.x & (NBUF - 1)) * (2 * 16);
#pragma unroll
    for (int c = 0; c < 16; ++c) {
        float v = acc[c];
        float q = v * v;
#pragma unroll
        for (int off = 32; off > 0; off >>= 1) {
            v += __shfl_xor(v, off, 64);
            q += __shfl_xor(q, off, 64);
        }
        if ((threadIdx.x & 63) == 0) {
            atomicAdd(&buf[c], v);
            atomicAdd(&buf[16 + c], q);
        }
    }
}

// ---------------------------------------------------------------------------
// Stage 1: Cin=16 (bf16 32B rows, 2MB L2-resident), Cout=32 tiled by 16.
// Round-4-proven shape: W tile in LDS (27.6KB, 5 blocks/CU), idx preload via
// PLAIN loads (L1 caches the 6912B/wave window), GRP=3 gather staging.
// Grid (N5/256, 2).
// ---------------------------------------------------------------------------
__global__ void __launch_bounds__(256) conv1_kernel(
    const u32x4* __restrict__ xb, const int* __restrict__ neigh,
    const float* __restrict__ W, float* __restrict__ y,
    float* __restrict__ stats)
{
    __shared__ float Wlds[27 * 16 * 16];
    const int cobase = blockIdx.y * 16;

    for (int i = threadIdx.x; i < 27 * 16 * 16; i += 256) {
        int k = i >> 4, c = i & 15;
        Wlds[i] = W[k * 32 + cobase + c];
    }
    __syncthreads();

    const int node = blockIdx.x * 256 + threadIdx.x;
    const int* nrow = neigh + (size_t)node * 27;

    int idx[27];
#pragma unroll
    for (int j = 0; j < 27; ++j) idx[j] = nrow[j];

    float acc[16];
#pragma unroll
    for (int c = 0; c < 16; ++c) acc[c] = 0.f;

#pragma unroll 1
    for (int g = 0; g < 27; g += 3) {
        u32x4 xa[3], xc[3];
#pragma unroll
        for (int u = 0; u < 3; ++u) {
            const size_t r = (size_t)idx[g + u] * 2;
            xa[u] = xb[r];
            xc[u] = xb[r + 1];
        }
#pragma unroll
        for (int u = 0; u < 3; ++u) {
            const int j = g + u;
            float xv[16];
            xv[0]  = bf_lo(xa[u].x); xv[1]  = bf_hi(xa[u].x);
            xv[2]  = bf_lo(xa[u].y); xv[3]  = bf_hi(xa[u].y);
            xv[4]  = bf_lo(xa[u].z); xv[5]  = bf_hi(xa[u].z);
            xv[6]  = bf_lo(xa[u].w); xv[7]  = bf_hi(xa[u].w);
            xv[8]  = bf_lo(xc[u].x); xv[9]  = bf_hi(xc[u].x);
            xv[10] = bf_lo(xc[u].y); xv[11] = bf_hi(xc[u].y);
            xv[12] = bf_lo(xc[u].z); xv[13] = bf_hi(xc[u].z);
            xv[14] = bf_lo(xc[u].w); xv[15] = bf_hi(xc[u].w);
#pragma unroll
            for (int k = 0; k < 16; ++k) {
                const f32x4* wv = (const f32x4*)&Wlds[(j * 16 + k) * 16];
#pragma unroll
                for (int c4 = 0; c4 < 4; ++c4) {
                    const f32x4 w = wv[c4];
                    acc[c4 * 4 + 0] = fmaf(xv[k], w.x, acc[c4 * 4 + 0]);
                    acc[c4 * 4 + 1] = fmaf(xv[k], w.y, acc[c4 * 4 + 1]);
                    acc[c4 * 4 + 2] = fmaf(xv[k], w.z, acc[c4 * 4 + 2]);
                    acc[c4 * 4 + 3] = fmaf(xv[k], w.w, acc[c4 * 4 + 3]);
                }
            }
        }
    }

    f32x4* yr = (f32x4*)(y + (size_t)node * 32 + cobase);
#pragma unroll
    for (int c4 = 0; c4 < 4; ++c4) {
        f32x4 v = { acc[c4 * 4 + 0], acc[c4 * 4 + 1], acc[c4 * 4 + 2], acc[c4 * 4 + 3] };
        __builtin_nontemporal_store(v, yr + c4);
    }

    float* buf = stats + (blockIdx.x & (NBUF - 1)) * (2 * 32);
#pragma unroll
    for (int c = 0; c < 16; ++c) {
        float v = acc[c];
        float q = v * v;
#pragma unroll
        for (int off = 32; off > 0; off >>= 1) {
            v += __shfl_xor(v, off, 64);
            q += __shfl_xor(q, off, 64);
        }
        if ((threadIdx.x & 63) == 0) {
            atomicAdd(&buf[cobase + c], v);
            atomicAdd(&buf[32 + cobase + c], q);
        }
    }
}

// ---------------------------------------------------------------------------
// Stage 2: Cin=32 (bf16 64B rows), Cout=64. thread-per-(node, channel-quad),
// 16 nodes/block, idx in LDS, W fp32 straight from L2 (coalesced+reused).
// ---------------------------------------------------------------------------
__global__ void __launch_bounds__(256) conv2_kernel(
    const u32x4* __restrict__ xb, const int* __restrict__ neigh,
    const float* __restrict__ W, float* __restrict__ y,
    float* __restrict__ stats)
{
    __shared__ int idxlds[16 * 27];
    const int nbase = blockIdx.x * 16;
    for (int i = threadIdx.x; i < 16 * 27; i += 256) {
        int n = i / 27, j = i - n * 27;
        idxlds[i] = neigh[(size_t)(nbase + n) * 27 + j];
    }
    __syncthreads();

    const int ln = threadIdx.x >> 4;
    const int c4 = threadIdx.x & 15;
    const int node = nbase + ln;

    f32x4 acc = { 0.f, 0.f, 0.f, 0.f };

#pragma unroll 1
    for (int j = 0; j < 27; ++j) {
        const int nb = idxlds[ln * 27 + j];
        const u32x4* xr = xb + (size_t)nb * 4;
        u32x4 xq[4];
#pragma unroll
        for (int q = 0; q < 4; ++q) xq[q] = xr[q];
#pragma unroll
        for (int q = 0; q < 4; ++q) {
            float xv[8];
            xv[0] = bf_lo(xq[q].x); xv[1] = bf_hi(xq[q].x);
            xv[2] = bf_lo(xq[q].y); xv[3] = bf_hi(xq[q].y);
            xv[4] = bf_lo(xq[q].z); xv[5] = bf_hi(xq[q].z);
            xv[6] = bf_lo(xq[q].w); xv[7] = bf_hi(xq[q].w);
#pragma unroll
            for (int h = 0; h < 8; ++h) {
                const int k = q * 8 + h;
                const f32x4 w = *(const f32x4*)(W + ((size_t)j * 32 + k) * 64 + c4 * 4);
                acc.x = fmaf(xv[h], w.x, acc.x);
                acc.y = fmaf(xv[h], w.y, acc.y);
                acc.z = fmaf(xv[h], w.z, acc.z);
                acc.w = fmaf(xv[h], w.w, acc.w);
            }
        }
    }

    __builtin_nontemporal_store(acc, (f32x4*)(y + (size_t)node * 64 + c4 * 4));

    float sx = acc.x, sy = acc.y, sz = acc.z, sw = acc.w;
    float qx = acc.x * acc.x, qy = acc.y * acc.y, qz = acc.z * acc.z, qw = acc.w * acc.w;
#pragma unroll
    for (int off = 16; off <= 32; off <<= 1) {
        sx += __shfl_xor(sx, off, 64);  sy += __shfl_xor(sy, off, 64);
        sz += __shfl_xor(sz, off, 64);  sw += __shfl_xor(sw, off, 64);
        qx += __shfl_xor(qx, off, 64);  qy += __shfl_xor(qy, off, 64);
        qz += __shfl_xor(qz, off, 64);  qw += __shfl_xor(qw, off, 64);
    }
    if ((threadIdx.x & 63) < 16) {
        float* buf = stats + (blockIdx.x & (NBUF - 1)) * (2 * 64);
        atomicAdd(&buf[c4 * 4 + 0], sx);
        atomicAdd(&buf[c4 * 4 + 1], sy);
        atomicAdd(&buf[c4 * 4 + 2], sz);
        atomicAdd(&buf[c4 * 4 + 3], sw);
        atomicAdd(&buf[64 + c4 * 4 + 0], qx);
        atomicAdd(&buf[64 + c4 * 4 + 1], qy);
        atomicAdd(&buf[64 + c4 * 4 + 2], qz);
        atomicAdd(&buf[64 + c4 * 4 + 3], qw);
    }
}

// ---------------------------------------------------------------------------
// Fused BN-finalize (per-block recompute) + affine + ReLU + 8-sibling maxpool.
// ---------------------------------------------------------------------------
template<int COUT, bool BF16OUT>
__global__ void __launch_bounds__(256) pool_fin_kernel(
    const float* __restrict__ y, const float* __restrict__ stats,
    const float* __restrict__ gamma, const float* __restrict__ beta,
    void* __restrict__ xout, float invN, int total2)
{
    __shared__ float ss[2 * COUT];
    if (threadIdx.x < COUT) {
        const int c = threadIdx.x;
        float s = 0.f, q = 0.f;
        for (int b = 0; b < NBUF; ++b) {
            s += stats[b * 2 * COUT + c];
            q += stats[b * 2 * COUT + COUT + c];
        }
        const float mean = s * invN;
        const float var  = fmaf(-mean, mean, q * invN);
        const float sc   = gamma[c] * rsqrtf(var + BN_EPS);
        ss[c]        = sc;
        ss[COUT + c] = fmaf(-mean, sc, beta[c]);
    }
    __syncthreads();

    const int t = blockIdx.x * 256 + threadIdx.x;
    if (t >= total2) return;
    const int p  = t / (COUT / 2);
    const int c2 = (t % (COUT / 2)) * 2;
    const float sc0 = ss[c2],     sh0 = ss[COUT + c2];
    const float sc1 = ss[c2 + 1], sh1 = ss[COUT + c2 + 1];
    const float* yr = y + (size_t)p * 8 * COUT + c2;
    float m0 = -3.4e38f, m1 = -3.4e38f;
#pragma unroll
    for (int i = 0; i < 8; ++i) {
        const f32x2 v = __builtin_nontemporal_load((const f32x2*)(yr + i * COUT));
        m0 = fmaxf(m0, fmaf(v.x, sc0, sh0));
        m1 = fmaxf(m1, fmaf(v.y, sc1, sh1));
    }
    m0 = fmaxf(m0, 0.f);
    m1 = fmaxf(m1, 0.f);
    if (BF16OUT) {
        ((unsigned*)xout)[t] = pack_bf16(m0, m1);
    } else {
        f32x2 r = { m0, m1 };
        ((f32x2*)xout)[t] = r;
    }
}

// ---------------------------------------------------------------------------
// octree2voxel scatter with transpose: out[b][c][i][j][k] = x3[n][c], r=vox[n]
// ---------------------------------------------------------------------------
__global__ void __launch_bounds__(256) scatter_kernel(
    const float* __restrict__ x3, const int* __restrict__ vox,
    float* __restrict__ out)
{
    const int t = blockIdx.x * 256 + threadIdx.x;  // 1024*64 threads
    const int n = t >> 6, c = t & 63;
    const int r = vox[n];
    out[((r >> 9) << 15) + (c << 9) + (r & 511)] = x3[t];
}

extern "C" void kernel_launch(void* const* d_in, const int* in_sizes, int n_in,
                              void* d_out, int out_size, void* d_ws, size_t ws_size,
                              hipStream_t stream)
{
    const float* data = (const float*)d_in[0];
    const float* W0   = (const float*)d_in[1];
    const float* g0   = (const float*)d_in[2];
    const float* b0   = (const float*)d_in[3];
    const float* W1   = (const float*)d_in[4];
    const float* g1   = (const float*)d_in[5];
    const float* b1   = (const float*)d_in[6];
    const float* W2   = (const float*)d_in[7];
    const float* g2   = (const float*)d_in[8];
    const float* b2   = (const float*)d_in[9];
    const int* neigh0 = (const int*)d_in[10];
    const int* neigh1 = (const int*)d_in[11];
    const int* neigh2 = (const int*)d_in[12];
    const int* vox    = (const int*)d_in[13];

    const int N6 = 524288, N5 = 65536, N4 = 8192, N3 = 1024;

    float* ws = (float*)d_ws;
    const size_t off_y0  = 0;                                 // N6*16
    const size_t off_xb1 = off_y0 + (size_t)N6 * 16;          // N5*8  (bf16 x1)
    const size_t off_y1  = off_xb1 + (size_t)N5 * 8;          // N5*32
    const size_t off_xb0 = off_y1;                            // N6*2  (bf16 x0, alias)
    const size_t off_xb2 = off_y1 + (size_t)N5 * 32;          // N4*16 (bf16 x2)
    const size_t off_y2  = off_xb2 + (size_t)N4 * 16;         // N4*64
    const size_t off_x3  = off_y2 + (size_t)N4 * 64;          // N3*64
    const size_t off_st0 = off_x3 + (size_t)N3 * 64;          // NBUF*2*16
    const size_t off_st1 = off_st0 + NBUF * 2 * 16;           // NBUF*2*32
    const size_t off_st2 = off_st1 + NBUF * 2 * 32;           // NBUF*2*64

    (void)hipMemsetAsync(ws + off_st0, 0, (size_t)(NBUF * 2 * (16 + 32 + 64)) * sizeof(float), stream);

    // stage 0: cast data -> bf16 table (4MB), conv with L1-bypass gathers
    cast_bf16_kernel<<<N6 / 256, 256, 0, stream>>>(
        (const f32x4*)data, (u32x2*)(ws + off_xb0), N6);
    conv0_kernel<<<N6 / 256, 256, 0, stream>>>(
        (const unsigned long long*)(ws + off_xb0), neigh0, W0, ws + off_y0, ws + off_st0);
    pool_fin_kernel<16, true><<<(N5 * 8) / 256, 256, 0, stream>>>(
        ws + off_y0, ws + off_st0, g0, b0, ws + off_xb1, 1.f / N6, N5 * 8);

    // stage 1
    conv1_kernel<<<dim3(N5 / 256, 2), 256, 0, stream>>>(
        (const u32x4*)(ws + off_xb1), neigh1, W1, ws + off_y1, ws + off_st1);
    pool_fin_kernel<32, true><<<(N4 * 16) / 256, 256, 0, stream>>>(
        ws + off_y1, ws + off_st1, g1, b1, ws + off_xb2, 1.f / N5, N4 * 16);

    // stage 2
    conv2_kernel<<<N4 / 16, 256, 0, stream>>>(
        (const u32x4*)(ws + off_xb2), neigh2, W2, ws + off_y2, ws + off_st2);
    pool_fin_kernel<64, false><<<(N3 * 32) / 256, 256, 0, stream>>>(
        ws + off_y2, ws + off_st2, g2, b2, ws + off_x3, 1.f / N4, N3 * 32);

    // octree2voxel
    (void)hipMemsetAsync(d_out, 0, (size_t)out_size * sizeof(float), stream);
    scatter_kernel<<<(N3 * 64) / 256, 256, 0, stream>>>(ws + off_x3, vox, (float*)d_out);
}

// Round 8
// 249.195 us; speedup vs baseline: 1.2595x; 1.0013x over previous
//
#include <hip/hip_runtime.h>

#define BN_EPS 1e-5f
#define NBUF 64   // spread buffers for stat atomics

typedef float        f32x4 __attribute__((ext_vector_type(4)));
typedef float        f32x2 __attribute__((ext_vector_type(2)));
typedef unsigned int u32x2 __attribute__((ext_vector_type(2)));
typedef unsigned int u32x4 __attribute__((ext_vector_type(4)));

__device__ inline unsigned pack_bf16(float a, float b) {
    unsigned ua = __float_as_uint(a);
    unsigned ub = __float_as_uint(b);
    ua = (ua + 0x7fffu + ((ua >> 16) & 1u)) >> 16;
    ub = (ub + 0x7fffu + ((ub >> 16) & 1u)) >> 16;
    return ua | (ub << 16);
}
__device__ inline float bf_lo(unsigned u) { return __uint_as_float(u << 16); }
__device__ inline float bf_hi(unsigned u) { return __uint_as_float(u & 0xffff0000u); }

// ---------------------------------------------------------------------------
// Cast fp32 -> packed bf16 (RNE). One thread = 4 floats -> 2 uints.
// ---------------------------------------------------------------------------
__global__ void __launch_bounds__(256) cast_bf16_kernel(
    const f32x4* __restrict__ in, u32x2* __restrict__ out, int n4)
{
    const int t = blockIdx.x * 256 + threadIdx.x;
    if (t >= n4) return;
    const f32x4 v = in[t];
    u32x2 r;
    r.x = pack_bf16(v.x, v.y);
    r.y = pack_bf16(v.z, v.w);
    out[t] = r;
}

// ---------------------------------------------------------------------------
// Stage 0 (role-inverted): block = 128 nodes.
// Phase 1: cooperative gather of 128*27 rows (8B) into LDS - coalesced idx,
//          1 request per row (request count unchanged), 14-deep MLP.
// Phase 2: thread = (ln, c4): nodes {ln, ln+64}, couts [4c4,4c4+4).
//          Per j: 2 conflict-free ds_read_b64 (stride-27 odd => 16 distinct
//          banks) + W from GLOBAL at 4-distinct-16B wave addresses (W0 =
//          6.9KB, L1-resident, 1 line/inst). No W broadcast through LDS.
// ---------------------------------------------------------------------------
__global__ void __launch_bounds__(256) conv0_kernel(
    const u32x2* __restrict__ xb, const int* __restrict__ neigh,
    const float* __restrict__ W, float* __restrict__ y,
    float* __restrict__ stats)
{
    __shared__ u32x2 xs[128 * 27];

    const int nbase = blockIdx.x * 128;
    {
        const int* nb = neigh + (size_t)nbase * 27;
#pragma unroll
        for (int i = 0; i < 14; ++i) {
            const int r = threadIdx.x + 256 * i;
            if (r < 128 * 27) xs[r] = xb[nb[r]];
        }
    }
    __syncthreads();

    const int ln = threadIdx.x >> 2;   // 0..63
    const int c4 = threadIdx.x & 3;    // cout quad 0..3

    float a0[4] = {0.f, 0.f, 0.f, 0.f};
    float a1[4] = {0.f, 0.f, 0.f, 0.f};

#pragma unroll
    for (int j = 0; j < 27; ++j) {
        const u32x2 rA = xs[ln * 27 + j];
        const u32x2 rB = xs[(ln + 64) * 27 + j];
        float xA[4], xB[4];
        xA[0] = bf_lo(rA.x); xA[1] = bf_hi(rA.x);
        xA[2] = bf_lo(rA.y); xA[3] = bf_hi(rA.y);
        xB[0] = bf_lo(rB.x); xB[1] = bf_hi(rB.x);
        xB[2] = bf_lo(rB.y); xB[3] = bf_hi(rB.y);
#pragma unroll
        for (int kk = 0; kk < 4; ++kk) {
            const f32x4 w = *(const f32x4*)(W + ((j * 4 + kk) << 4) + (c4 << 2));
#pragma unroll
            for (int i = 0; i < 4; ++i) {
                a0[i] = fmaf(xA[kk], w[i], a0[i]);
                a1[i] = fmaf(xB[kk], w[i], a1[i]);
            }
        }
    }

    {
        f32x4 v0 = { a0[0], a0[1], a0[2], a0[3] };
        f32x4 v1 = { a1[0], a1[1], a1[2], a1[3] };
        __builtin_nontemporal_store(v0, (f32x4*)(y + (size_t)(nbase + ln) * 16 + (c4 << 2)));
        __builtin_nontemporal_store(v1, (f32x4*)(y + (size_t)(nbase + 64 + ln) * 16 + (c4 << 2)));
    }

    // stats: reduce over ln lanes (wave bits 2..5), lanes 0..3 hold c4 0..3
    float* buf = stats + (blockIdx.x & (NBUF - 1)) * (2 * 16);
#pragma unroll
    for (int i = 0; i < 4; ++i) {
        float v = a0[i] + a1[i];
        float q = a0[i] * a0[i] + a1[i] * a1[i];
#pragma unroll
        for (int off = 4; off <= 32; off <<= 1) {
            v += __shfl_xor(v, off, 64);
            q += __shfl_xor(q, off, 64);
        }
        if ((threadIdx.x & 63) < 4) {
            atomicAdd(&buf[(c4 << 2) + i], v);
            atomicAdd(&buf[16 + (c4 << 2) + i], q);
        }
    }
}

// ---------------------------------------------------------------------------
// Stage 1: unchanged round-7 shape (W tile 16 in LDS, grid (N5/256, 2),
// plain idx preload, GRP=3 gather staging).
// ---------------------------------------------------------------------------
__global__ void __launch_bounds__(256) conv1_kernel(
    const u32x4* __restrict__ xb, const int* __restrict__ neigh,
    const float* __restrict__ W, float* __restrict__ y,
    float* __restrict__ stats)
{
    __shared__ float Wlds[27 * 16 * 16];
    const int cobase = blockIdx.y * 16;

    for (int i = threadIdx.x; i < 27 * 16 * 16; i += 256) {
        int k = i >> 4, c = i & 15;
        Wlds[i] = W[k * 32 + cobase + c];
    }
    __syncthreads();

    const int node = blockIdx.x * 256 + threadIdx.x;
    const int* nrow = neigh + (size_t)node * 27;

    int idx[27];
#pragma unroll
    for (int j = 0; j < 27; ++j) idx[j] = nrow[j];

    float acc[16];
#pragma unroll
    for (int c = 0; c < 16; ++c) acc[c] = 0.f;

#pragma unroll 1
    for (int g = 0; g < 27; g += 3) {
        u32x4 xa[3], xc[3];
#pragma unroll
        for (int u = 0; u < 3; ++u) {
            const size_t r = (size_t)idx[g + u] * 2;
            xa[u] = xb[r];
            xc[u] = xb[r + 1];
        }
#pragma unroll
        for (int u = 0; u < 3; ++u) {
            const int j = g + u;
            float xv[16];
            xv[0]  = bf_lo(xa[u].x); xv[1]  = bf_hi(xa[u].x);
            xv[2]  = bf_lo(xa[u].y); xv[3]  = bf_hi(xa[u].y);
            xv[4]  = bf_lo(xa[u].z); xv[5]  = bf_hi(xa[u].z);
            xv[6]  = bf_lo(xa[u].w); xv[7]  = bf_hi(xa[u].w);
            xv[8]  = bf_lo(xc[u].x); xv[9]  = bf_hi(xc[u].x);
            xv[10] = bf_lo(xc[u].y); xv[11] = bf_hi(xc[u].y);
            xv[12] = bf_lo(xc[u].z); xv[13] = bf_hi(xc[u].z);
            xv[14] = bf_lo(xc[u].w); xv[15] = bf_hi(xc[u].w);
#pragma unroll
            for (int k = 0; k < 16; ++k) {
                const f32x4* wv = (const f32x4*)&Wlds[(j * 16 + k) * 16];
#pragma unroll
                for (int c4 = 0; c4 < 4; ++c4) {
                    const f32x4 w = wv[c4];
                    acc[c4 * 4 + 0] = fmaf(xv[k], w.x, acc[c4 * 4 + 0]);
                    acc[c4 * 4 + 1] = fmaf(xv[k], w.y, acc[c4 * 4 + 1]);
                    acc[c4 * 4 + 2] = fmaf(xv[k], w.z, acc[c4 * 4 + 2]);
                    acc[c4 * 4 + 3] = fmaf(xv[k], w.w, acc[c4 * 4 + 3]);
                }
            }
        }
    }

    f32x4* yr = (f32x4*)(y + (size_t)node * 32 + cobase);
#pragma unroll
    for (int c4 = 0; c4 < 4; ++c4) {
        f32x4 v = { acc[c4 * 4 + 0], acc[c4 * 4 + 1], acc[c4 * 4 + 2], acc[c4 * 4 + 3] };
        __builtin_nontemporal_store(v, yr + c4);
    }

    float* buf = stats + (blockIdx.x & (NBUF - 1)) * (2 * 32);
#pragma unroll
    for (int c = 0; c < 16; ++c) {
        float v = acc[c];
        float q = v * v;
#pragma unroll
        for (int off = 32; off > 0; off >>= 1) {
            v += __shfl_xor(v, off, 64);
            q += __shfl_xor(q, off, 64);
        }
        if ((threadIdx.x & 63) == 0) {
            atomicAdd(&buf[cobase + c], v);
            atomicAdd(&buf[32 + cobase + c], q);
        }
    }
}

// ---------------------------------------------------------------------------
// Stage 2: unchanged round-7 shape.
// ---------------------------------------------------------------------------
__global__ void __launch_bounds__(256) conv2_kernel(
    const u32x4* __restrict__ xb, const int* __restrict__ neigh,
    const float* __restrict__ W, float* __restrict__ y,
    float* __restrict__ stats)
{
    __shared__ int idxlds[16 * 27];
    const int nbase = blockIdx.x * 16;
    for (int i = threadIdx.x; i < 16 * 27; i += 256) {
        int n = i / 27, j = i - n * 27;
        idxlds[i] = neigh[(size_t)(nbase + n) * 27 + j];
    }
    __syncthreads();

    const int ln = threadIdx.x >> 4;
    const int c4 = threadIdx.x & 15;
    const int node = nbase + ln;

    f32x4 acc = { 0.f, 0.f, 0.f, 0.f };

#pragma unroll 1
    for (int j = 0; j < 27; ++j) {
        const int nb = idxlds[ln * 27 + j];
        const u32x4* xr = xb + (size_t)nb * 4;
        u32x4 xq[4];
#pragma unroll
        for (int q = 0; q < 4; ++q) xq[q] = xr[q];
#pragma unroll
        for (int q = 0; q < 4; ++q) {
            float xv[8];
            xv[0] = bf_lo(xq[q].x); xv[1] = bf_hi(xq[q].x);
            xv[2] = bf_lo(xq[q].y); xv[3] = bf_hi(xq[q].y);
            xv[4] = bf_lo(xq[q].z); xv[5] = bf_hi(xq[q].z);
            xv[6] = bf_lo(xq[q].w); xv[7] = bf_hi(xq[q].w);
#pragma unroll
            for (int h = 0; h < 8; ++h) {
                const int k = q * 8 + h;
                const f32x4 w = *(const f32x4*)(W + ((size_t)j * 32 + k) * 64 + c4 * 4);
                acc.x = fmaf(xv[h], w.x, acc.x);
                acc.y = fmaf(xv[h], w.y, acc.y);
                acc.z = fmaf(xv[h], w.z, acc.z);
                acc.w = fmaf(xv[h], w.w, acc.w);
            }
        }
    }

    __builtin_nontemporal_store(acc, (f32x4*)(y + (size_t)node * 64 + c4 * 4));

    float sx = acc.x, sy = acc.y, sz = acc.z, sw = acc.w;
    float qx = acc.x * acc.x, qy = acc.y * acc.y, qz = acc.z * acc.z, qw = acc.w * acc.w;
#pragma unroll
    for (int off = 16; off <= 32; off <<= 1) {
        sx += __shfl_xor(sx, off, 64);  sy += __shfl_xor(sy, off, 64);
        sz += __shfl_xor(sz, off, 64);  sw += __shfl_xor(sw, off, 64);
        qx += __shfl_xor(qx, off, 64);  qy += __shfl_xor(qy, off, 64);
        qz += __shfl_xor(qz, off, 64);  qw += __shfl_xor(qw, off, 64);
    }
    if ((threadIdx.x & 63) < 16) {
        float* buf = stats + (blockIdx.x & (NBUF - 1)) * (2 * 64);
        atomicAdd(&buf[c4 * 4 + 0], sx);
        atomicAdd(&buf[c4 * 4 + 1], sy);
        atomicAdd(&buf[c4 * 4 + 2], sz);
        atomicAdd(&buf[c4 * 4 + 3], sw);
        atomicAdd(&buf[64 + c4 * 4 + 0], qx);
        atomicAdd(&buf[64 + c4 * 4 + 1], qy);
        atomicAdd(&buf[64 + c4 * 4 + 2], qz);
        atomicAdd(&buf[64 + c4 * 4 + 3], qw);
    }
}

// ---------------------------------------------------------------------------
// Fused BN-finalize + affine + ReLU + 8-sibling maxpool (stages 0,1).
// ---------------------------------------------------------------------------
template<int COUT, bool BF16OUT>
__global__ void __launch_bounds__(256) pool_fin_kernel(
    const float* __restrict__ y, const float* __restrict__ stats,
    const float* __restrict__ gamma, const float* __restrict__ beta,
    void* __restrict__ xout, float invN, int total2)
{
    __shared__ float ss[2 * COUT];
    if (threadIdx.x < COUT) {
        const int c = threadIdx.x;
        float s = 0.f, q = 0.f;
        for (int b = 0; b < NBUF; ++b) {
            s += stats[b * 2 * COUT + c];
            q += stats[b * 2 * COUT + COUT + c];
        }
        const float mean = s * invN;
        const float var  = fmaf(-mean, mean, q * invN);
        const float sc   = gamma[c] * rsqrtf(var + BN_EPS);
        ss[c]        = sc;
        ss[COUT + c] = fmaf(-mean, sc, beta[c]);
    }
    __syncthreads();

    const int t = blockIdx.x * 256 + threadIdx.x;
    if (t >= total2) return;
    const int p  = t / (COUT / 2);
    const int c2 = (t % (COUT / 2)) * 2;
    const float sc0 = ss[c2],     sh0 = ss[COUT + c2];
    const float sc1 = ss[c2 + 1], sh1 = ss[COUT + c2 + 1];
    const float* yr = y + (size_t)p * 8 * COUT + c2;
    float m0 = -3.4e38f, m1 = -3.4e38f;
#pragma unroll
    for (int i = 0; i < 8; ++i) {
        const f32x2 v = __builtin_nontemporal_load((const f32x2*)(yr + i * COUT));
        m0 = fmaxf(m0, fmaf(v.x, sc0, sh0));
        m1 = fmaxf(m1, fmaf(v.y, sc1, sh1));
    }
    m0 = fmaxf(m0, 0.f);
    m1 = fmaxf(m1, 0.f);
    if (BF16OUT) {
        ((unsigned*)xout)[t] = pack_bf16(m0, m1);
    } else {
        f32x2 r = { m0, m1 };
        ((f32x2*)xout)[t] = r;
    }
}

// ---------------------------------------------------------------------------
// Stage-2 epilogue: BN-finalize + affine + ReLU + maxpool + octree2voxel
// scatter fused. thread t -> (parent p, channel pair c2); r = vox[p];
// out[b][c][ijk] with b = r>>9, ijk = r&511.
// ---------------------------------------------------------------------------
__global__ void __launch_bounds__(256) pool_fin2_scatter_kernel(
    const float* __restrict__ y, const float* __restrict__ stats,
    const float* __restrict__ gamma, const float* __restrict__ beta,
    const int* __restrict__ vox, float* __restrict__ out, float invN)
{
    __shared__ float ss[128];
    if (threadIdx.x < 64) {
        const int c = threadIdx.x;
        float s = 0.f, q = 0.f;
        for (int b = 0; b < NBUF; ++b) {
            s += stats[b * 128 + c];
            q += stats[b * 128 + 64 + c];
        }
        const float mean = s * invN;
        const float var  = fmaf(-mean, mean, q * invN);
        const float sc   = gamma[c] * rsqrtf(var + BN_EPS);
        ss[c]      = sc;
        ss[64 + c] = fmaf(-mean, sc, beta[c]);
    }
    __syncthreads();

    const int t = blockIdx.x * 256 + threadIdx.x;   // N3*32 = 32768 threads
    const int p  = t >> 5;
    const int c2 = (t & 31) * 2;
    const float sc0 = ss[c2],     sh0 = ss[64 + c2];
    const float sc1 = ss[c2 + 1], sh1 = ss[64 + c2 + 1];
    const float* yr = y + (size_t)p * 8 * 64 + c2;
    float m0 = -3.4e38f, m1 = -3.4e38f;
#pragma unroll
    for (int i = 0; i < 8; ++i) {
        const f32x2 v = __builtin_nontemporal_load((const f32x2*)(yr + i * 64));
        m0 = fmaxf(m0, fmaf(v.x, sc0, sh0));
        m1 = fmaxf(m1, fmaf(v.y, sc1, sh1));
    }
    m0 = fmaxf(m0, 0.f);
    m1 = fmaxf(m1, 0.f);

    const int r = vox[p];
    const int base = ((r >> 9) << 15) + (r & 511);
    out[base + (c2 << 9)]       = m0;
    out[base + ((c2 + 1) << 9)] = m1;
}

extern "C" void kernel_launch(void* const* d_in, const int* in_sizes, int n_in,
                              void* d_out, int out_size, void* d_ws, size_t ws_size,
                              hipStream_t stream)
{
    const float* data = (const float*)d_in[0];
    const float* W0   = (const float*)d_in[1];
    const float* g0   = (const float*)d_in[2];
    const float* b0   = (const float*)d_in[3];
    const float* W1   = (const float*)d_in[4];
    const float* g1   = (const float*)d_in[5];
    const float* b1   = (const float*)d_in[6];
    const float* W2   = (const float*)d_in[7];
    const float* g2   = (const float*)d_in[8];
    const float* b2   = (const float*)d_in[9];
    const int* neigh0 = (const int*)d_in[10];
    const int* neigh1 = (const int*)d_in[11];
    const int* neigh2 = (const int*)d_in[12];
    const int* vox    = (const int*)d_in[13];

    const int N6 = 524288, N5 = 65536, N4 = 8192, N3 = 1024;

    float* ws = (float*)d_ws;
    const size_t off_y0  = 0;                                 // N6*16
    const size_t off_xb1 = off_y0 + (size_t)N6 * 16;          // N5*8  (bf16 x1)
    const size_t off_y1  = off_xb1 + (size_t)N5 * 8;          // N5*32
    const size_t off_xb0 = off_y1;                            // N6*2  (bf16 x0, alias)
    const size_t off_xb2 = off_y1 + (size_t)N5 * 32;          // N4*16 (bf16 x2)
    const size_t off_y2  = off_xb2 + (size_t)N4 * 16;         // N4*64
    const size_t off_st0 = off_y2 + (size_t)N4 * 64;          // NBUF*2*16
    const size_t off_st1 = off_st0 + NBUF * 2 * 16;           // NBUF*2*32
    const size_t off_st2 = off_st1 + NBUF * 2 * 32;           // NBUF*2*64

    (void)hipMemsetAsync(ws + off_st0, 0, (size_t)(NBUF * 2 * (16 + 32 + 64)) * sizeof(float), stream);

    // stage 0: cast data -> bf16 table (4MB, L2-resident), role-inverted conv
    cast_bf16_kernel<<<N6 / 256, 256, 0, stream>>>(
        (const f32x4*)data, (u32x2*)(ws + off_xb0), N6);
    conv0_kernel<<<N6 / 128, 256, 0, stream>>>(
        (const u32x2*)(ws + off_xb0), neigh0, W0, ws + off_y0, ws + off_st0);
    pool_fin_kernel<16, true><<<(N5 * 8) / 256, 256, 0, stream>>>(
        ws + off_y0, ws + off_st0, g0, b0, ws + off_xb1, 1.f / N6, N5 * 8);

    // stage 1
    conv1_kernel<<<dim3(N5 / 256, 2), 256, 0, stream>>>(
        (const u32x4*)(ws + off_xb1), neigh1, W1, ws + off_y1, ws + off_st1);
    pool_fin_kernel<32, true><<<(N4 * 16) / 256, 256, 0, stream>>>(
        ws + off_y1, ws + off_st1, g1, b1, ws + off_xb2, 1.f / N5, N4 * 16);

    // stage 2 + fused pool/BN/scatter epilogue
    conv2_kernel<<<N4 / 16, 256, 0, stream>>>(
        (const u32x4*)(ws + off_xb2), neigh2, W2, ws + off_y2, ws + off_st2);
    (void)hipMemsetAsync(d_out, 0, (size_t)out_size * sizeof(float), stream);
    pool_fin2_scatter_kernel<<<(N3 * 32) / 256, 256, 0, stream>>>(
        ws + off_y2, ws + off_st2, g2, b2, vox, (float*)d_out, 1.f / N4);
}